// Round 6
// baseline (145.744 us; speedup 1.0000x reference)
//
#include <hip/hip_runtime.h>

// Problem constants
#define Vn 128
#define Bn 16
#define Nn 127
#define BTn 2048
#define TRS 20   // merged bf16 table row stride in dwords (80 B)

// round-to-nearest-even f32 -> bf16 bits
__device__ __forceinline__ unsigned rneb(float f) {
    unsigned u = __float_as_uint(f);
    return (u + 0x7fffu + ((u >> 16) & 1u)) >> 16;
}
// enc[s][e] = 1 + (e-7)*(s-15)/128  (exact in fp32)
__device__ __forceinline__ float encf(int s, float e7) {
    return fmaf(e7, (float)(s - 15) * 0.0078125f, 1.0f);
}
__device__ __forceinline__ float bflo(unsigned p) { return __uint_as_float(p << 16); }
__device__ __forceinline__ float bfhi(unsigned p) { return __uint_as_float(p & 0xffff0000u); }

// One wave (64 lanes) per bt. All barriers are intra-wave (cheap).
__global__ __launch_bounds__(64, 4) void memnet_main(
    const float* __restrict__ node_fts, const float* __restrict__ edge_fts,
    const float* __restrict__ graph_fts, const float* __restrict__ adjm,
    const float* __restrict__ qb, const float* __restrict__ sb,
    const float* __restrict__ ob, const float* __restrict__ mc,
    const float* __restrict__ wout, const float* __restrict__ wfin,
    float* __restrict__ ret)
{
    __shared__ __align__(16) unsigned tblL[128 * TRS]; // dword[e] = ob_bf16<<16 | sb_bf16
    __shared__ __align__(8) unsigned cjB[128 * 8];     // Cj bf16 pairs: [m][e/2]
    __shared__ float scoresL[128];
    __shared__ float probsL[128];
    __shared__ __align__(16) float uL[16];
    __shared__ __align__(16) float cCL[16];
    __shared__ float uoL[16];
    __shared__ float xL[128];

    const int l  = threadIdx.x;       // 0..63
    const int q  = l >> 2;            // quad 0..15
    const int j4 = l & 3;             // lane in quad
    const int eg4 = j4 * 4;           // e-group base
    const int bt = blockIdx.x;
    const int b  = bt >> 7;
    const int i  = bt & 127;          // 127 == graph-feature row
    const int row = b * 127 + i;      // valid only when i<127

    // ---- adjacency ballots (wave-uniform masks) ----
    bool aLo = false, aHi = false;
    if (i < 127) {
        aLo = (adjm[row * 127 + l] != 0.f);
        if (l < 63) aHi = (adjm[row * 127 + 64 + l] != 0.f);
    }
    const unsigned long long mk0 = __ballot(aLo);
    const unsigned long long mk1 = __ballot(aHi);

    // ---- u[e], cC[e], k0 (lane = e*4+g, g sums 8 s-values) ----
    float k0;
    {
        const int e = l >> 2, g = l & 3;
        const float e7 = (float)(e - 7);
        float ue = 0.f;
#pragma unroll
        for (int so = 0; so < 8; ++so) {
            int s = g * 8 + so;
            float qv = (i < 127) ? node_fts[row * 32 + s] : graph_fts[b * 32 + s];
            int qi = (int)qv; if (qi < 0) qi = 0;
            float w = (qi < 127) ? qb[qi * 16 + e] : 0.f;
            ue = fmaf(w, encf(s, e7), ue);
        }
        ue += __shfl_xor(ue, 1); ue += __shfl_xor(ue, 2);   // all 4 lanes of e have u[e]
        const float es = fmaf(e7, 0.125f, 32.f);            // sum_s enc[s][e], exact
        if (g == 0) { uL[e] = ue; cCL[e] = ob[e] * es; }
        float kv = (g == 0) ? sb[e] * es * ue : 0.f;
        kv += __shfl_xor(kv, 1);  kv += __shfl_xor(kv, 2);
        kv += __shfl_xor(kv, 4);  kv += __shfl_xor(kv, 8);
        kv += __shfl_xor(kv, 16); kv += __shfl_xor(kv, 32);
        k0 = kv;
    }

    // ---- stage merged bf16 table (127 rows + zero nil row) ----
#pragma unroll
    for (int k = 0; k < 8; ++k) {
        int c = l + 64 * k;
        int r = c >> 2, qd = c & 3;
        float4 s4 = make_float4(0.f, 0.f, 0.f, 0.f);
        float4 o4 = make_float4(0.f, 0.f, 0.f, 0.f);
        if (r < 127) {
            s4 = *(const float4*)&sb[r * 16 + qd * 4];
            o4 = *(const float4*)&ob[r * 16 + qd * 4];
        }
        uint4 pk;
        pk.x = (rneb(o4.x) << 16) | rneb(s4.x);
        pk.y = (rneb(o4.y) << 16) | rneb(s4.y);
        pk.z = (rneb(o4.z) << 16) | rneb(s4.z);
        pk.w = (rneb(o4.w) << 16) | rneb(s4.w);
        *(uint4*)&tblL[r * TRS + qd * 4] = pk;
    }
    __syncthreads();   // single-wave: cheap

    // ---- gather: 8 rounds, quad q handles slot m = r*16+q; edge prefetched 1 round ahead ----
    const float4 u4  = *(const float4*)&uL[eg4];
    const float4 cC4 = *(const float4*)&cCL[eg4];
    const float ef0 = (float)(eg4 - 7), ef1 = (float)(eg4 - 6);
    const float ef2 = (float)(eg4 - 5), ef3 = (float)(eg4 - 4);

    float4 nx0 = make_float4(0,0,0,0), nx1 = make_float4(0,0,0,0);
    bool na;
    {   // prefetch round 0
        int m = q;
        na = (mk0 >> m) & 1ull;
        if (na) {
            const float4* ep = (const float4*)&edge_fts[((((size_t)row) * 127 + m) * 32) + j4 * 8];
            nx0 = ep[0]; nx1 = ep[1];
        }
    }

    for (int r = 0; r < 8; ++r) {
        const int m = r * 16 + q;
        const bool a = na;
        const float4 c0 = nx0, c1 = nx1;
        const float4 mc4 = *(const float4*)&mc[m * 16 + eg4];   // L2-hot

        if (r < 7) {   // prefetch next round
            int mn = (r + 1) * 16 + q;
            na = (((r + 1) < 4 ? mk0 : mk1) >> (mn & 63)) & 1ull;
            if (na) {
                const float4* ep = (const float4*)&edge_fts[((((size_t)row) * 127 + mn) * 32) + j4 * 8];
                nx0 = ep[0]; nx1 = ep[1];
            }
        }

        float4 aM = make_float4(0,0,0,0), aC = make_float4(0,0,0,0);
        if (a) {
            // pack my 8 indices (s = j4*8 .. j4*8+7) into 2 words
            unsigned p0 = (unsigned)(int)c0.x | ((unsigned)(int)c0.y << 8)
                        | ((unsigned)(int)c0.z << 16) | ((unsigned)(int)c0.w << 24);
            unsigned p1 = (unsigned)(int)c1.x | ((unsigned)(int)c1.y << 8)
                        | ((unsigned)(int)c1.z << 16) | ((unsigned)(int)c1.w << 24);
            // quad exchange -> every lane gets all 8 s-words (a is quad-uniform)
            unsigned o0 = __shfl_xor(p0, 1), o1 = __shfl_xor(p1, 1);
            unsigned q0 = (j4 & 1) ? o0 : p0, q1 = (j4 & 1) ? o1 : p1;
            unsigned q2 = (j4 & 1) ? p0 : o0, q3 = (j4 & 1) ? p1 : o1;
            unsigned t0 = __shfl_xor(q0, 2), t1 = __shfl_xor(q1, 2);
            unsigned t2 = __shfl_xor(q2, 2), t3 = __shfl_xor(q3, 2);
            unsigned w0 = (j4 & 2) ? t0 : q0, w1 = (j4 & 2) ? t1 : q1;
            unsigned w2 = (j4 & 2) ? t2 : q2, w3 = (j4 & 2) ? t3 : q3;
            unsigned w4 = (j4 & 2) ? q0 : t0, w5 = (j4 & 2) ? q1 : t1;
            unsigned w6 = (j4 & 2) ? q2 : t2, w7 = (j4 & 2) ? q3 : t3;

            auto gstep = [&](unsigned wv, int sbase) {
#pragma unroll
                for (int j = 0; j < 4; ++j) {
                    const int s = sbase + j;
                    int ix = (int)((wv >> (8 * j)) & 0xFF);
                    const uint4 pk = *(const uint4*)&tblL[ix * TRS + eg4];
                    float e0 = encf(s, ef0), e1 = encf(s, ef1);
                    float e2 = encf(s, ef2), e3 = encf(s, ef3);
                    aM.x = fmaf(bflo(pk.x), e0, aM.x); aC.x = fmaf(bfhi(pk.x), e0, aC.x);
                    aM.y = fmaf(bflo(pk.y), e1, aM.y); aC.y = fmaf(bfhi(pk.y), e1, aC.y);
                    aM.z = fmaf(bflo(pk.z), e2, aM.z); aC.z = fmaf(bfhi(pk.z), e2, aC.z);
                    aM.w = fmaf(bflo(pk.w), e3, aM.w); aC.w = fmaf(bfhi(pk.w), e3, aC.w);
                }
            };
            gstep(w0, 0);  gstep(w1, 4);  gstep(w2, 8);  gstep(w3, 12);
            gstep(w4, 16); gstep(w5, 20); gstep(w6, 24); gstep(w7, 28);
        }

        // score = dot(aM + mc, u); inactive gets +k0 (exact closed form)
        float p = (aM.x + mc4.x) * u4.x + (aM.y + mc4.y) * u4.y
                + (aM.z + mc4.z) * u4.z + (aM.w + mc4.w) * u4.w;
        p += __shfl_xor(p, 1); p += __shfl_xor(p, 2);
        if (j4 == 0) scoresL[m] = p + (a ? 0.f : k0);

        // Cj (bf16 pairs) to LDS
        float4 cc = a ? aC : cC4;
        unsigned d0 = (rneb(cc.y) << 16) | rneb(cc.x);
        unsigned d1 = (rneb(cc.w) << 16) | rneb(cc.z);
        *(uint2*)&cjB[m * 8 + j4 * 2] = make_uint2(d0, d1);
    }
    __syncthreads();

    // ---- softmax over 128 slots (pure shuffle) ----
    {
        float s0 = scoresL[l], s1 = scoresL[l + 64];
        float mx = fmaxf(s0, s1);
#pragma unroll
        for (int st = 1; st < 64; st <<= 1) mx = fmaxf(mx, __shfl_xor(mx, st));
        float e0 = __expf(s0 - mx), e1 = __expf(s1 - mx);
        float sm = e0 + e1;
#pragma unroll
        for (int st = 1; st < 64; st <<= 1) sm += __shfl_xor(sm, st);
        float inv = 1.f / sm;
        probsL[l] = e0 * inv;
        probsL[l + 64] = e1 * inv;
    }
    __syncthreads();

    // ---- o[e] = sum_m probs[m] * Cj[m][e] ----
    {
        const int e = l & 15, ch = l >> 4;    // 4 chunks of 32 slots
        float oa = 0.f;
#pragma unroll 8
        for (int k = 0; k < 32; ++k) {
            int m = ch * 32 + k;
            unsigned d = cjB[m * 8 + (e >> 1)];
            float cv = (e & 1) ? bfhi(d) : bflo(d);
            oa = fmaf(probsL[m], cv, oa);
        }
        oa += __shfl_xor(oa, 16); oa += __shfl_xor(oa, 32);
        if (l < 16) uoL[l] = uL[l] + oa;
    }
    __syncthreads();

    // ---- x = relu((u+o) @ W_out), 2 outputs per lane ----
    {
        float rx = 0.f, ry = 0.f;
#pragma unroll
        for (int e = 0; e < 16; ++e) {
            float uoe = uoL[e];
            const float2 w2 = *(const float2*)&wout[e * 128 + 2 * l];
            rx = fmaf(uoe, w2.x, rx); ry = fmaf(uoe, w2.y, ry);
        }
        xL[2 * l]     = fmaxf(rx, 0.f);
        xL[2 * l + 1] = fmaxf(ry, 0.f);
    }
    __syncthreads();
    // ---- ret = x @ W_fin ----
    {
        float rx = 0.f, ry = 0.f;
#pragma unroll 8
        for (int ll = 0; ll < 128; ++ll) {
            float xv = xL[ll];                                  // broadcast
            const float2 w2 = *(const float2*)&wfin[ll * 128 + 2 * l];
            rx = fmaf(xv, w2.x, rx); ry = fmaf(xv, w2.y, ry);
        }
        *(float2*)&ret[bt * 128 + 2 * l] = make_float2(rx, ry);
    }
}

// out[b,i,v] = ret[b,i,v] + ret[b,127,v]
__global__ void memnet_out(const float* __restrict__ ret, float* __restrict__ out)
{
    int idx = blockIdx.x * 256 + threadIdx.x;
    if (idx >= Bn * Nn * Vn) return;
    int v = idx & 127;
    int r = idx >> 7;          // b*127 + i
    int b = r / 127;
    int i = r - b * 127;
    out[idx] = ret[(b * 128 + i) * 128 + v] + ret[(b * 128 + 127) * 128 + v];
}

extern "C" void kernel_launch(void* const* d_in, const int* in_sizes, int n_in,
                              void* d_out, int out_size, void* d_ws, size_t ws_size,
                              hipStream_t stream)
{
    const float* node  = (const float*)d_in[0];
    const float* edge  = (const float*)d_in[1];
    const float* graph = (const float*)d_in[2];
    const float* adjm  = (const float*)d_in[3];
    // d_in[4] = hidden (unused), d_in[5] = enc (analytic in-kernel)
    const float* qb    = (const float*)d_in[6];
    const float* sb    = (const float*)d_in[7];
    const float* ob    = (const float*)d_in[8];
    const float* mc    = (const float*)d_in[9];
    // d_in[10] = W_int (unused, num_hops == 1)
    const float* wout  = (const float*)d_in[11];
    const float* wfin  = (const float*)d_in[12];

    float* ws = (float*)d_ws;   // BTn * 128 floats = 1 MB scratch

    memnet_main<<<BTn, 64, 0, stream>>>(node, edge, graph, adjm, qb,
                                        sb, ob, mc, wout, wfin, ws);
    const int total = Bn * Nn * Vn;
    memnet_out<<<(total + 255) / 256, 256, 0, stream>>>(ws, (float*)d_out);
}